// Round 2
// baseline (181.931 us; speedup 1.0000x reference)
//
#include <hip/hip_runtime.h>

// ---------------------------------------------------------------------------
// BatchedGraphSAGE: out = BN(relu(l2norm(cat[x@Wx^T+bx, m1@Wn^T+bn, ...])))
// mean(gather(x)) @ W^T == mean(gather(x @ W^T)): project once, gather the
// 2 MB bf16 projected tensor (L2-resident).
// Pipeline: k0 (W->bf16, 0.5MB) ; k1 GEMM fp32-A/bf16-B -> xWx(bf16,+bias),
// xWn(bf16) ; k2 row-per-wave gather+l2norm+relu -> h(bf16) + BN partials
// (LDS-reduced, non-atomic) ; k3 fold partials -> affine coefs ; k4 apply.
// ---------------------------------------------------------------------------

typedef short  s16x8 __attribute__((ext_vector_type(8)));
typedef float  f32x4 __attribute__((ext_vector_type(4)));
typedef unsigned short u16x4 __attribute__((ext_vector_type(4)));

// ws layout (bytes), total ~15 MB
#define OFF_WCAT   (0u)            // Wcat [512][256] bf16  : 256 KB
#define OFF_XWX    (262144u)       // xWx  [4096][256] bf16 : 2 MB (bias added)
#define OFF_XWN    (2359296u)      // xWn  [4096][256] bf16 : 2 MB
#define OFF_HBUF   (4456448u)      // h    [4096][1024] bf16: 8 MB
#define OFF_PART   (12845056u)     // part [256][2048] f32  : 2 MB
#define OFF_COEFA  (14942208u)     // A[1024] f32
#define OFF_COEFB  (14946304u)     // B[1024] f32

__device__ __forceinline__ unsigned short f2bf(float f) {
    unsigned int u = __float_as_uint(f);
    u = (u + 0x7FFFu + ((u >> 16) & 1u)) >> 16;          // RNE
    return (unsigned short)u;
}
__device__ __forceinline__ float bflo(unsigned int d) {   // low bf16 of dword
    return __uint_as_float(d << 16);
}
__device__ __forceinline__ float bfhi(unsigned int d) {   // high bf16 of dword
    return __uint_as_float(d & 0xFFFF0000u);
}

// k0: convert [Wx;Wn] (131072 f32) -> Wcat bf16
__global__ __launch_bounds__(256) void k0_convert(
    const float* __restrict__ Wx, const float* __restrict__ Wn,
    unsigned short* __restrict__ Wcat)
{
    int e = (blockIdx.x * 256 + threadIdx.x) * 4;        // 128 blocks
    const float* src = (e < 65536) ? &Wx[e] : &Wn[e - 65536];
    float4 v = *(const float4*)src;
    u16x4 o; o[0]=f2bf(v.x); o[1]=f2bf(v.y); o[2]=f2bf(v.z); o[3]=f2bf(v.w);
    *(u16x4*)&Wcat[e] = o;
}

// k1: [4096][512] = x(f32) @ Wcat^T. Cols 0..255 -> xWx bf16 (+bias),
// 256..511 -> xWn bf16. 16x16x32 bf16 MFMA, A converted in-register.
__global__ __launch_bounds__(256) void k1_gemm(
    const float* __restrict__ x, const unsigned short* __restrict__ W,
    const float* __restrict__ bx,
    unsigned short* __restrict__ xWx, unsigned short* __restrict__ xWn)
{
    const int tid = threadIdx.x;
    const int w = tid >> 6, l = tid & 63;
    const int l15 = l & 15, lhi = l >> 4;
    const int rowBase = blockIdx.x * 64 + w * 16;
    const int colBase = blockIdx.y * 64;

    f32x4 acc[4] = {};
    const float*          ap = &x[(rowBase + l15) * 256 + lhi * 8];
    const unsigned short* wp = &W[(colBase + l15) * 256 + lhi * 8];
    #pragma unroll
    for (int kk = 0; kk < 256; kk += 32) {
        float4 a0 = *(const float4*)(ap + kk);
        float4 a1 = *(const float4*)(ap + kk + 4);
        s16x8 a;
        a[0]=(short)f2bf(a0.x); a[1]=(short)f2bf(a0.y);
        a[2]=(short)f2bf(a0.z); a[3]=(short)f2bf(a0.w);
        a[4]=(short)f2bf(a1.x); a[5]=(short)f2bf(a1.y);
        a[6]=(short)f2bf(a1.z); a[7]=(short)f2bf(a1.w);
        #pragma unroll
        for (int c = 0; c < 4; ++c) {
            s16x8 b = *(const s16x8*)(wp + c * 16 * 256 + kk);
            acc[c] = __builtin_amdgcn_mfma_f32_16x16x32_bf16(a, b, acc[c], 0, 0, 0);
        }
    }
    // C/D layout: col = lane&15, row = (lane>>4)*4 + reg
    const int row0 = rowBase + lhi * 4;
    if (colBase < 256) {
        #pragma unroll
        for (int c = 0; c < 4; ++c) {
            float bxv = bx[colBase + c * 16 + l15];
            #pragma unroll
            for (int r = 0; r < 4; ++r)
                xWx[(row0 + r) * 256 + colBase + c * 16 + l15] = f2bf(acc[c][r] + bxv);
        }
    } else {
        #pragma unroll
        for (int c = 0; c < 4; ++c)
            #pragma unroll
            for (int r = 0; r < 4; ++r)
                xWn[(row0 + r) * 256 + (colBase - 256) + c * 16 + l15] = f2bf(acc[c][r]);
    }
}

// k2: one wave per (b,n) row. Lane l owns channels {4l..4l+3} of each of the
// 4 segments; gathers are 8B uint2 loads (4 bf16 channels). L2-normalize via
// 6-step shfl_xor, relu, write h bf16, accumulate BN partials in registers,
// LDS-reduce across the 4 waves, one non-atomic global write per block.
__global__ __launch_bounds__(256) void k2_rows(
    const unsigned short* __restrict__ xWx, const unsigned short* __restrict__ xWn,
    const int* __restrict__ idx1, const int* __restrict__ idx2,
    const int* __restrict__ idx3, const float* __restrict__ bn,
    unsigned short* __restrict__ hbuf, float* __restrict__ part)
{
    __shared__ int   lidx[4][96];
    __shared__ float lpart[4][2048];
    const int t = threadIdx.x, w = t >> 6, l = t & 63;
    const float4 bnv = *(const float4*)&bn[l * 4];
    f32x4 sA[4] = {}, sQ[4] = {};

    #pragma unroll 1
    for (int rr = 0; rr < 4; ++rr) {
        const int r = blockIdx.x * 16 + w * 4 + rr;
        const int b = r >> 9, n = r & 511;
        __syncthreads();                       // prior-iter reads done
        if (l < 32) {
            lidx[w][l]      = idx1[n * 32 + l];
            lidx[w][64 + l] = idx3[n * 32 + l];
        } else {
            lidx[w][l]      = idx2[n * 32 + (l & 31)];
        }
        __syncthreads();                       // idx visible

        const unsigned short* basep = &xWn[(unsigned)b * (512u * 256u)];
        f32x4 m1 = {}, m2 = {}, m3 = {};
        #pragma unroll
        for (int k = 0; k < 32; ++k) {
            uint2 d = *(const uint2*)(basep + lidx[w][k] * 256 + l * 4);
            m1[0] += bflo(d.x); m1[1] += bfhi(d.x);
            m1[2] += bflo(d.y); m1[3] += bfhi(d.y);
        }
        #pragma unroll
        for (int k = 0; k < 32; ++k) {
            uint2 d = *(const uint2*)(basep + lidx[w][32 + k] * 256 + l * 4);
            m2[0] += bflo(d.x); m2[1] += bfhi(d.x);
            m2[2] += bflo(d.y); m2[3] += bfhi(d.y);
        }
        #pragma unroll
        for (int k = 0; k < 32; ++k) {
            uint2 d = *(const uint2*)(basep + lidx[w][64 + k] * 256 + l * 4);
            m3[0] += bflo(d.x); m3[1] += bfhi(d.x);
            m3[2] += bflo(d.y); m3[3] += bfhi(d.y);
        }

        uint2 hd = *(const uint2*)(xWx + r * 256 + l * 4);  // bias pre-added
        f32x4 hseg[4];
        hseg[0][0] = bflo(hd.x); hseg[0][1] = bfhi(hd.x);
        hseg[0][2] = bflo(hd.y); hseg[0][3] = bfhi(hd.y);
        #pragma unroll
        for (int j = 0; j < 4; ++j) {
            hseg[1][j] = m1[j] * (1.f / 32.f) + bnv[j];
            hseg[2][j] = m2[j] * (1.f / 32.f) + bnv[j];
            hseg[3][j] = m3[j] * (1.f / 32.f) + bnv[j];
        }
        float p = 0.f;
        #pragma unroll
        for (int s = 0; s < 4; ++s)
            #pragma unroll
            for (int j = 0; j < 4; ++j) p += hseg[s][j] * hseg[s][j];
        #pragma unroll
        for (int m = 32; m > 0; m >>= 1) p += __shfl_xor(p, m);
        const float invn = 1.0f / fmaxf(sqrtf(p), 1e-12f);

        unsigned short* hr = &hbuf[(unsigned)r * 1024u];
        #pragma unroll
        for (int s = 0; s < 4; ++s) {
            f32x4 v;
            #pragma unroll
            for (int j = 0; j < 4; ++j) v[j] = fmaxf(hseg[s][j] * invn, 0.f);
            uint2 o;
            o.x = (unsigned)f2bf(v[0]) | ((unsigned)f2bf(v[1]) << 16);
            o.y = (unsigned)f2bf(v[2]) | ((unsigned)f2bf(v[3]) << 16);
            *(uint2*)(hr + s * 256 + l * 4) = o;
            #pragma unroll
            for (int j = 0; j < 4; ++j) { sA[s][j] += v[j]; sQ[s][j] += v[j]*v[j]; }
        }
    }
    // block-reduce BN partials: per-wave LDS stage, then 4-way fold
    #pragma unroll
    for (int s = 0; s < 4; ++s)
        #pragma unroll
        for (int j = 0; j < 4; ++j) {
            lpart[w][       s * 256 + l * 4 + j] = sA[s][j];
            lpart[w][1024 + s * 256 + l * 4 + j] = sQ[s][j];
        }
    __syncthreads();
    for (int c = t; c < 2048; c += 256)
        part[blockIdx.x * 2048 + c] =
            lpart[0][c] + lpart[1][c] + lpart[2][c] + lpart[3][c];
}

// k3: fold 256 per-block partials -> per-channel BN affine coefs
__global__ __launch_bounds__(256) void k3_coef(
    const float* __restrict__ part, const float* __restrict__ gamma,
    const float* __restrict__ beta, float* __restrict__ cA, float* __restrict__ cB)
{
    int c = blockIdx.x * 256 + threadIdx.x;   // 4 blocks -> 1024 channels
    float s = 0.f, s2 = 0.f;
    #pragma unroll 32
    for (int rep = 0; rep < 256; ++rep) {
        s  += part[rep * 2048 + c];
        s2 += part[rep * 2048 + 1024 + c];
    }
    float mu  = s  * (1.f / 4096.f);
    float var = s2 * (1.f / 4096.f) - mu * mu;
    float a = gamma[c] / sqrtf(var + 1e-5f);
    cA[c] = a;
    cB[c] = beta[c] - mu * a;
}

// k4: out = h * A[c] + B[c]; h bf16 (8B/thread in), out f32 (16B/thread)
__global__ __launch_bounds__(256) void k4_apply(
    const unsigned short* __restrict__ hbuf, const float* __restrict__ cA,
    const float* __restrict__ cB, float* __restrict__ out)
{
    int gid = blockIdx.x * 256 + threadIdx.x;
    int c0 = (gid & 255) * 4;                 // (gid*4) mod 1024
    uint2 hd = *(const uint2*)(hbuf + (unsigned)gid * 4u);
    float4 a = *(const float4*)&cA[c0];
    float4 b = *(const float4*)&cB[c0];
    float4 o;
    o.x = bflo(hd.x) * a.x + b.x;  o.y = bfhi(hd.x) * a.y + b.y;
    o.z = bflo(hd.y) * a.z + b.z;  o.w = bfhi(hd.y) * a.w + b.w;
    *(float4*)&out[(unsigned)gid * 4u] = o;
}

extern "C" void kernel_launch(void* const* d_in, const int* in_sizes, int n_in,
                              void* d_out, int out_size, void* d_ws, size_t ws_size,
                              hipStream_t stream)
{
    const float* x     = (const float*)d_in[0];
    const int*   idx1  = (const int*)  d_in[1];
    const int*   idx2  = (const int*)  d_in[2];
    const int*   idx3  = (const int*)  d_in[3];
    const float* Wx    = (const float*)d_in[4];
    const float* bx    = (const float*)d_in[5];
    const float* Wn    = (const float*)d_in[6];
    const float* bn    = (const float*)d_in[7];
    const float* gamma = (const float*)d_in[8];
    const float* beta  = (const float*)d_in[9];

    char* ws = (char*)d_ws;
    unsigned short* Wcat = (unsigned short*)(ws + OFF_WCAT);
    unsigned short* xWx  = (unsigned short*)(ws + OFF_XWX);
    unsigned short* xWn  = (unsigned short*)(ws + OFF_XWN);
    unsigned short* hbuf = (unsigned short*)(ws + OFF_HBUF);
    float*          part = (float*)         (ws + OFF_PART);
    float*          cA   = (float*)         (ws + OFF_COEFA);
    float*          cB   = (float*)         (ws + OFF_COEFB);

    k0_convert<<<128, 256, 0, stream>>>(Wx, Wn, Wcat);
    k1_gemm<<<dim3(64, 8), 256, 0, stream>>>(x, Wcat, bx, xWx, xWn);
    k2_rows<<<256, 256, 0, stream>>>(xWx, xWn, idx1, idx2, idx3, bn, hbuf, part);
    k3_coef<<<4, 256, 0, stream>>>(part, gamma, beta, cA, cB);
    k4_apply<<<4096, 256, 0, stream>>>(hbuf, cA, cB, (float*)d_out);
}

// Round 5
// 122.684 us; speedup vs baseline: 1.4829x; 1.4829x over previous
//
#include <hip/hip_runtime.h>

// ---------------------------------------------------------------------------
// BatchedGraphSAGE: out = BN(relu(l2norm(cat[x@Wx^T+bx, m1@Wn^T+bn, ...])))
// mean(gather(x)) @ W^T == mean(gather(x @ W^T)): project once, gather the
// 2 MB bf16 projected tensor (L2-resident).
// k0 (W->bf16) ; k1 GEMM fp32-A/bf16-B -> xWx(bf16,+bias), xWn(bf16) ;
// k2 wave-per-row gather+l2norm+relu -> h(bf16), BN partials -> 32 replicated
// atomic buffers (1024 blocks = 4/CU for latency hiding) ;
// k3 fold 32x2048 -> affine coefs ; k4 apply.
// (Resubmission: rounds 3 and 4 both failed on infra before benching this.)
// ---------------------------------------------------------------------------

typedef short  s16x8 __attribute__((ext_vector_type(8)));
typedef float  f32x4 __attribute__((ext_vector_type(4)));
typedef unsigned short u16x4 __attribute__((ext_vector_type(4)));

#define NREP 32

// ws layout (bytes), total ~13.1 MB
#define OFF_WCAT   (0u)            // Wcat [512][256] bf16  : 256 KB
#define OFF_XWX    (262144u)       // xWx  [4096][256] bf16 : 2 MB (bias added)
#define OFF_XWN    (2359296u)      // xWn  [4096][256] bf16 : 2 MB
#define OFF_HBUF   (4456448u)      // h    [4096][1024] bf16: 8 MB
#define OFF_SUMS   (12845056u)     // sums [32][2048] f32   : 256 KB
#define OFF_COEFA  (13107200u)     // A[1024] f32
#define OFF_COEFB  (13111296u)     // B[1024] f32

__device__ __forceinline__ unsigned short f2bf(float f) {
    unsigned int u = __float_as_uint(f);
    u = (u + 0x7FFFu + ((u >> 16) & 1u)) >> 16;          // RNE
    return (unsigned short)u;
}
__device__ __forceinline__ float bflo(unsigned int d) {
    return __uint_as_float(d << 16);
}
__device__ __forceinline__ float bfhi(unsigned int d) {
    return __uint_as_float(d & 0xFFFF0000u);
}

// k0: convert [Wx;Wn] (131072 f32) -> Wcat bf16
__global__ __launch_bounds__(256) void k0_convert(
    const float* __restrict__ Wx, const float* __restrict__ Wn,
    unsigned short* __restrict__ Wcat)
{
    int e = (blockIdx.x * 256 + threadIdx.x) * 4;        // 128 blocks
    const float* src = (e < 65536) ? &Wx[e] : &Wn[e - 65536];
    float4 v = *(const float4*)src;
    u16x4 o; o[0]=f2bf(v.x); o[1]=f2bf(v.y); o[2]=f2bf(v.z); o[3]=f2bf(v.w);
    *(u16x4*)&Wcat[e] = o;
}

// k1: [4096][512] = x(f32) @ Wcat^T. Cols 0..255 -> xWx bf16 (+bias),
// 256..511 -> xWn bf16. 16x16x32 bf16 MFMA, A converted in-register.
__global__ __launch_bounds__(256) void k1_gemm(
    const float* __restrict__ x, const unsigned short* __restrict__ W,
    const float* __restrict__ bx,
    unsigned short* __restrict__ xWx, unsigned short* __restrict__ xWn)
{
    const int tid = threadIdx.x;
    const int w = tid >> 6, l = tid & 63;
    const int l15 = l & 15, lhi = l >> 4;
    const int rowBase = blockIdx.x * 64 + w * 16;
    const int colBase = blockIdx.y * 64;

    f32x4 acc[4] = {};
    const float*          ap = &x[(rowBase + l15) * 256 + lhi * 8];
    const unsigned short* wp = &W[(colBase + l15) * 256 + lhi * 8];
    #pragma unroll
    for (int kk = 0; kk < 256; kk += 32) {
        float4 a0 = *(const float4*)(ap + kk);
        float4 a1 = *(const float4*)(ap + kk + 4);
        s16x8 a;
        a[0]=(short)f2bf(a0.x); a[1]=(short)f2bf(a0.y);
        a[2]=(short)f2bf(a0.z); a[3]=(short)f2bf(a0.w);
        a[4]=(short)f2bf(a1.x); a[5]=(short)f2bf(a1.y);
        a[6]=(short)f2bf(a1.z); a[7]=(short)f2bf(a1.w);
        #pragma unroll
        for (int c = 0; c < 4; ++c) {
            s16x8 b = *(const s16x8*)(wp + c * 16 * 256 + kk);
            acc[c] = __builtin_amdgcn_mfma_f32_16x16x32_bf16(a, b, acc[c], 0, 0, 0);
        }
    }
    // C/D layout: col = lane&15, row = (lane>>4)*4 + reg
    const int row0 = rowBase + lhi * 4;
    if (colBase < 256) {
        #pragma unroll
        for (int c = 0; c < 4; ++c) {
            float bxv = bx[colBase + c * 16 + l15];
            #pragma unroll
            for (int r = 0; r < 4; ++r)
                xWx[(row0 + r) * 256 + colBase + c * 16 + l15] = f2bf(acc[c][r] + bxv);
        }
    } else {
        #pragma unroll
        for (int c = 0; c < 4; ++c)
            #pragma unroll
            for (int r = 0; r < 4; ++r)
                xWn[(row0 + r) * 256 + (colBase - 256) + c * 16 + l15] = f2bf(acc[c][r]);
    }
}

// k2: one wave per (b,n) row, 1024 blocks (4 blocks/CU, 16 waves/CU).
// Lane l owns channels {4l..4l+3} of each segment via 8B uint2 gathers.
// L2-normalize via shfl_xor, relu, write h bf16; BN partials folded across
// the block's 4 waves in LDS, then atomicAdd into 32 replicated buffers.
__global__ __launch_bounds__(256) void k2_rows(
    const unsigned short* __restrict__ xWx, const unsigned short* __restrict__ xWn,
    const int* __restrict__ idx1, const int* __restrict__ idx2,
    const int* __restrict__ idx3, const float* __restrict__ bn,
    unsigned short* __restrict__ hbuf, float* __restrict__ sums)
{
    __shared__ int   lidx[4][96];
    __shared__ float lpart[4][2048];
    const int t = threadIdx.x, w = t >> 6, l = t & 63;
    const int r = blockIdx.x * 4 + w;
    const int b = r >> 9, n = r & 511;

    if (l < 32) {
        lidx[w][l]      = idx1[n * 32 + l];
        lidx[w][64 + l] = idx3[n * 32 + l];
    } else {
        lidx[w][l]      = idx2[n * 32 + (l & 31)];   // slots 32..63
    }
    __syncthreads();

    const float4 bnv = *(const float4*)&bn[l * 4];
    const unsigned short* basep = &xWn[(unsigned)b * (512u * 256u)];
    f32x4 m1 = {}, m2 = {}, m3 = {};
    #pragma unroll
    for (int k = 0; k < 32; ++k) {
        uint2 d = *(const uint2*)(basep + lidx[w][k] * 256 + l * 4);
        m1[0] += bflo(d.x); m1[1] += bfhi(d.x);
        m1[2] += bflo(d.y); m1[3] += bfhi(d.y);
    }
    #pragma unroll
    for (int k = 0; k < 32; ++k) {
        uint2 d = *(const uint2*)(basep + lidx[w][32 + k] * 256 + l * 4);
        m2[0] += bflo(d.x); m2[1] += bfhi(d.x);
        m2[2] += bflo(d.y); m2[3] += bfhi(d.y);
    }
    #pragma unroll
    for (int k = 0; k < 32; ++k) {
        uint2 d = *(const uint2*)(basep + lidx[w][64 + k] * 256 + l * 4);
        m3[0] += bflo(d.x); m3[1] += bfhi(d.x);
        m3[2] += bflo(d.y); m3[3] += bfhi(d.y);
    }

    uint2 hd = *(const uint2*)(xWx + r * 256 + l * 4);   // bias pre-added
    f32x4 hseg[4];
    hseg[0][0] = bflo(hd.x); hseg[0][1] = bfhi(hd.x);
    hseg[0][2] = bflo(hd.y); hseg[0][3] = bfhi(hd.y);
    #pragma unroll
    for (int j = 0; j < 4; ++j) {
        hseg[1][j] = m1[j] * (1.f / 32.f) + bnv[j];
        hseg[2][j] = m2[j] * (1.f / 32.f) + bnv[j];
        hseg[3][j] = m3[j] * (1.f / 32.f) + bnv[j];
    }
    float p = 0.f;
    #pragma unroll
    for (int s = 0; s < 4; ++s)
        #pragma unroll
        for (int j = 0; j < 4; ++j) p += hseg[s][j] * hseg[s][j];
    #pragma unroll
    for (int m = 32; m > 0; m >>= 1) p += __shfl_xor(p, m);
    const float invn = 1.0f / fmaxf(sqrtf(p), 1e-12f);

    unsigned short* hr = &hbuf[(unsigned)r * 1024u];
    #pragma unroll
    for (int s = 0; s < 4; ++s) {
        f32x4 v;
        #pragma unroll
        for (int j = 0; j < 4; ++j) v[j] = fmaxf(hseg[s][j] * invn, 0.f);
        uint2 o;
        o.x = (unsigned)f2bf(v[0]) | ((unsigned)f2bf(v[1]) << 16);
        o.y = (unsigned)f2bf(v[2]) | ((unsigned)f2bf(v[3]) << 16);
        *(uint2*)(hr + s * 256 + l * 4) = o;
        #pragma unroll
        for (int j = 0; j < 4; ++j) {
            lpart[w][       s * 256 + l * 4 + j] = v[j];
            lpart[w][1024 + s * 256 + l * 4 + j] = v[j] * v[j];
        }
    }
    __syncthreads();
    float* sb = &sums[(blockIdx.x & (NREP - 1)) * 2048];
    for (int c = t; c < 2048; c += 256)
        atomicAdd(&sb[c], lpart[0][c] + lpart[1][c] + lpart[2][c] + lpart[3][c]);
}

// k3: fold 32 replicated buffers -> per-channel BN affine coefs
__global__ __launch_bounds__(256) void k3_coef(
    const float* __restrict__ sums, const float* __restrict__ gamma,
    const float* __restrict__ beta, float* __restrict__ cA, float* __restrict__ cB)
{
    int c = blockIdx.x * 256 + threadIdx.x;   // 4 blocks -> 1024 channels
    float s = 0.f, s2 = 0.f;
    #pragma unroll
    for (int rep = 0; rep < NREP; ++rep) {
        s  += sums[rep * 2048 + c];
        s2 += sums[rep * 2048 + 1024 + c];
    }
    float mu  = s  * (1.f / 4096.f);
    float var = s2 * (1.f / 4096.f) - mu * mu;
    float a = gamma[c] / sqrtf(var + 1e-5f);
    cA[c] = a;
    cB[c] = beta[c] - mu * a;
}

// k4: out = h * A[c] + B[c]; h bf16 (8B/thread in), out f32 (16B/thread)
__global__ __launch_bounds__(256) void k4_apply(
    const unsigned short* __restrict__ hbuf, const float* __restrict__ cA,
    const float* __restrict__ cB, float* __restrict__ out)
{
    int gid = blockIdx.x * 256 + threadIdx.x;
    int c0 = (gid & 255) * 4;                 // (gid*4) mod 1024
    uint2 hd = *(const uint2*)(hbuf + (unsigned)gid * 4u);
    float4 a = *(const float4*)&cA[c0];
    float4 b = *(const float4*)&cB[c0];
    float4 o;
    o.x = bflo(hd.x) * a.x + b.x;  o.y = bfhi(hd.x) * a.y + b.y;
    o.z = bflo(hd.y) * a.z + b.z;  o.w = bfhi(hd.y) * a.w + b.w;
    *(float4*)&out[(unsigned)gid * 4u] = o;
}

extern "C" void kernel_launch(void* const* d_in, const int* in_sizes, int n_in,
                              void* d_out, int out_size, void* d_ws, size_t ws_size,
                              hipStream_t stream)
{
    const float* x     = (const float*)d_in[0];
    const int*   idx1  = (const int*)  d_in[1];
    const int*   idx2  = (const int*)  d_in[2];
    const int*   idx3  = (const int*)  d_in[3];
    const float* Wx    = (const float*)d_in[4];
    const float* bx    = (const float*)d_in[5];
    const float* Wn    = (const float*)d_in[6];
    const float* bn    = (const float*)d_in[7];
    const float* gamma = (const float*)d_in[8];
    const float* beta  = (const float*)d_in[9];

    char* ws = (char*)d_ws;
    unsigned short* Wcat = (unsigned short*)(ws + OFF_WCAT);
    unsigned short* xWx  = (unsigned short*)(ws + OFF_XWX);
    unsigned short* xWn  = (unsigned short*)(ws + OFF_XWN);
    unsigned short* hbuf = (unsigned short*)(ws + OFF_HBUF);
    float*          sums = (float*)         (ws + OFF_SUMS);
    float*          cA   = (float*)         (ws + OFF_COEFA);
    float*          cB   = (float*)         (ws + OFF_COEFB);

    k0_convert<<<128, 256, 0, stream>>>(Wx, Wn, Wcat);
    k1_gemm<<<dim3(64, 8), 256, 0, stream>>>(x, Wcat, bx, xWx, xWn);
    hipMemsetAsync(sums, 0, NREP * 2048 * sizeof(float), stream);
    k2_rows<<<1024, 256, 0, stream>>>(xWx, xWn, idx1, idx2, idx3, bn, hbuf, sums);
    k3_coef<<<4, 256, 0, stream>>>(sums, gamma, beta, cA, cB);
    k4_apply<<<4096, 256, 0, stream>>>(hbuf, cA, cB, (float*)d_out);
}